// Round 2
// baseline (2281.955 us; speedup 1.0000x reference)
//
#include <hip/hip_runtime.h>

// Problem constants (from reference setup_inputs)
constexpr int DN = 128, DE = 64, DG = 32, DO = 128;
constexpr int K1 = DN + DE + DG;  // 224 — edge MLP fan-in
constexpr int K2 = DN + DO;       // 256 — node MLP fan-in
constexpr float NEG_SLOPE = 0.01f;
constexpr float LN_EPS = 1e-5f;

constexpr int EPB = 16;  // edges per block
constexpr int NPB = 8;   // nodes per block

// ---------------------------------------------------------------------------
// Edge kernel: h1 = concat(x[src], edge_attr, u);  h = LN(leaky(h1@W1a+b1a));
// h2 = h@W1b + b1b; atomic scatter-add h2 into sums[dest], count into cnt.
// Block = 128 threads (thread j = output column), EPB edges per block.
// ---------------------------------------------------------------------------
__global__ __launch_bounds__(128) void edge_kernel(
    const float* __restrict__ x, const int* __restrict__ edge_index,
    const float* __restrict__ edge_attr, const float* __restrict__ u,
    const float* __restrict__ W1a, const float* __restrict__ b1a,
    const float* __restrict__ g1, const float* __restrict__ be1,
    const float* __restrict__ W1b, const float* __restrict__ b1b,
    float* __restrict__ sums, float* __restrict__ cnt, int E)
{
    __shared__ float s_in[EPB][K1];    // staged concat inputs
    __shared__ float s_hn[EPB][DO];    // post-LN hidden
    __shared__ float s_red[2][2][EPB]; // [wave][sum|sumsq][e]
    __shared__ int s_src[EPB];
    __shared__ int s_dst[EPB];

    const int tid = threadIdx.x;
    const int j = tid;                 // output column 0..127
    const int lane = tid & 63;
    const int wave = tid >> 6;
    const int ebase = blockIdx.x * EPB;
    const int evalid = min(EPB, E - ebase);

    if (tid < EPB) {
        int e = ebase + tid;
        s_src[tid] = (tid < evalid) ? edge_index[e] : 0;
        s_dst[tid] = (tid < evalid) ? edge_index[E + e] : 0;
    }
    __syncthreads();

    // Gather concat(x[src], edge_attr[e], u) into LDS. Coalesced over k.
    for (int idx = tid; idx < EPB * K1; idx += 128) {
        int e = idx / K1;
        int k = idx - e * K1;
        float v = 0.f;
        if (e < evalid) {
            if (k < DN)            v = x[(long)s_src[e] * DN + k];
            else if (k < DN + DE)  v = edge_attr[(long)(ebase + e) * DE + (k - DN)];
            else                   v = u[k - DN - DE];
        }
        s_in[e][k] = v;
    }
    __syncthreads();

    // Matmul 1: [EPB,224] @ [224,128]. Thread j owns column j for all edges.
    float acc[EPB];
#pragma unroll
    for (int e = 0; e < EPB; e++) acc[e] = 0.f;
    for (int k4 = 0; k4 < K1; k4 += 4) {
        const float w0 = W1a[(k4 + 0) * DO + j];
        const float w1 = W1a[(k4 + 1) * DO + j];
        const float w2 = W1a[(k4 + 2) * DO + j];
        const float w3 = W1a[(k4 + 3) * DO + j];
#pragma unroll
        for (int e = 0; e < EPB; e++) {
            const float4 h = *reinterpret_cast<const float4*>(&s_in[e][k4]);
            acc[e] = fmaf(h.x, w0, fmaf(h.y, w1, fmaf(h.z, w2, fmaf(h.w, w3, acc[e]))));
        }
    }

    // Bias + LeakyReLU
    const float ba = b1a[j];
#pragma unroll
    for (int e = 0; e < EPB; e++) {
        float v = acc[e] + ba;
        acc[e] = (v >= 0.f) ? v : NEG_SLOPE * v;
    }

    // LayerNorm over the 128 columns of each edge: wave shuffle + LDS combine
#pragma unroll
    for (int e = 0; e < EPB; e++) {
        float s = acc[e], s2 = acc[e] * acc[e];
        for (int off = 32; off; off >>= 1) {
            s += __shfl_down(s, off, 64);
            s2 += __shfl_down(s2, off, 64);
        }
        if (lane == 0) { s_red[wave][0][e] = s; s_red[wave][1][e] = s2; }
    }
    __syncthreads();

    const float g = g1[j], be = be1[j];
#pragma unroll
    for (int e = 0; e < EPB; e++) {
        float sum = s_red[0][0][e] + s_red[1][0][e];
        float sq  = s_red[0][1][e] + s_red[1][1][e];
        float mu = sum * (1.f / DO);
        float var = sq * (1.f / DO) - mu * mu;
        float rs = rsqrtf(var + LN_EPS);
        s_hn[e][j] = (acc[e] - mu) * rs * g + be;
    }
    __syncthreads();

    // Matmul 2: [EPB,128] @ [128,128]
    float acc2[EPB];
#pragma unroll
    for (int e = 0; e < EPB; e++) acc2[e] = 0.f;
    for (int k4 = 0; k4 < DO; k4 += 4) {
        const float w0 = W1b[(k4 + 0) * DO + j];
        const float w1 = W1b[(k4 + 1) * DO + j];
        const float w2 = W1b[(k4 + 2) * DO + j];
        const float w3 = W1b[(k4 + 3) * DO + j];
#pragma unroll
        for (int e = 0; e < EPB; e++) {
            const float4 h = *reinterpret_cast<const float4*>(&s_hn[e][k4]);
            acc2[e] = fmaf(h.x, w0, fmaf(h.y, w1, fmaf(h.z, w2, fmaf(h.w, w3, acc2[e]))));
        }
    }

    // Scatter: atomic add into per-dest sums + counts
    const float bb = b1b[j];
#pragma unroll
    for (int e = 0; e < EPB; e++) {
        if (e < evalid) {
            atomicAdd(&sums[(long)s_dst[e] * DO + j], acc2[e] + bb);
        }
    }
    if (tid < evalid) atomicAdd(&cnt[s_dst[tid]], 1.0f);
}

// ---------------------------------------------------------------------------
// Node kernel: h1 = concat(x[n], sums[n]/max(cnt,1));
// out = LN(leaky(h1@W2a+b2a)) @ W2b + b2b
// ---------------------------------------------------------------------------
__global__ __launch_bounds__(128) void node_kernel(
    const float* __restrict__ x, const float* __restrict__ sums,
    const float* __restrict__ cnt,
    const float* __restrict__ W2a, const float* __restrict__ b2a,
    const float* __restrict__ g2, const float* __restrict__ be2,
    const float* __restrict__ W2b, const float* __restrict__ b2b,
    float* __restrict__ out, int N)
{
    __shared__ float s_in[NPB][K2];
    __shared__ float s_hn[NPB][DO];
    __shared__ float s_red[2][2][NPB];

    const int tid = threadIdx.x;
    const int j = tid;
    const int lane = tid & 63;
    const int wave = tid >> 6;
    const int nbase = blockIdx.x * NPB;
    const int nvalid = min(NPB, N - nbase);

    // Gather concat(x[n], agg[n]); K2 = 256 so idx>>8 / idx&255
    for (int idx = tid; idx < NPB * K2; idx += 128) {
        int n = idx >> 8;
        int k = idx & 255;
        float v = 0.f;
        if (n < nvalid) {
            int node = nbase + n;
            if (k < DN) v = x[(long)node * DN + k];
            else {
                float c = cnt[node];
                c = (c > 1.f) ? c : 1.f;
                v = sums[(long)node * DO + (k - DN)] / c;
            }
        }
        s_in[n][k] = v;
    }
    __syncthreads();

    float acc[NPB];
#pragma unroll
    for (int n = 0; n < NPB; n++) acc[n] = 0.f;
    for (int k4 = 0; k4 < K2; k4 += 4) {
        const float w0 = W2a[(k4 + 0) * DO + j];
        const float w1 = W2a[(k4 + 1) * DO + j];
        const float w2 = W2a[(k4 + 2) * DO + j];
        const float w3 = W2a[(k4 + 3) * DO + j];
#pragma unroll
        for (int n = 0; n < NPB; n++) {
            const float4 h = *reinterpret_cast<const float4*>(&s_in[n][k4]);
            acc[n] = fmaf(h.x, w0, fmaf(h.y, w1, fmaf(h.z, w2, fmaf(h.w, w3, acc[n]))));
        }
    }

    const float ba = b2a[j];
#pragma unroll
    for (int n = 0; n < NPB; n++) {
        float v = acc[n] + ba;
        acc[n] = (v >= 0.f) ? v : NEG_SLOPE * v;
    }

#pragma unroll
    for (int n = 0; n < NPB; n++) {
        float s = acc[n], s2 = acc[n] * acc[n];
        for (int off = 32; off; off >>= 1) {
            s += __shfl_down(s, off, 64);
            s2 += __shfl_down(s2, off, 64);
        }
        if (lane == 0) { s_red[wave][0][n] = s; s_red[wave][1][n] = s2; }
    }
    __syncthreads();

    const float g = g2[j], be = be2[j];
#pragma unroll
    for (int n = 0; n < NPB; n++) {
        float sum = s_red[0][0][n] + s_red[1][0][n];
        float sq  = s_red[0][1][n] + s_red[1][1][n];
        float mu = sum * (1.f / DO);
        float var = sq * (1.f / DO) - mu * mu;
        float rs = rsqrtf(var + LN_EPS);
        s_hn[n][j] = (acc[n] - mu) * rs * g + be;
    }
    __syncthreads();

    float acc2[NPB];
#pragma unroll
    for (int n = 0; n < NPB; n++) acc2[n] = 0.f;
    for (int k4 = 0; k4 < DO; k4 += 4) {
        const float w0 = W2b[(k4 + 0) * DO + j];
        const float w1 = W2b[(k4 + 1) * DO + j];
        const float w2 = W2b[(k4 + 2) * DO + j];
        const float w3 = W2b[(k4 + 3) * DO + j];
#pragma unroll
        for (int n = 0; n < NPB; n++) {
            const float4 h = *reinterpret_cast<const float4*>(&s_hn[n][k4]);
            acc2[n] = fmaf(h.x, w0, fmaf(h.y, w1, fmaf(h.z, w2, fmaf(h.w, w3, acc2[n]))));
        }
    }

    const float bb = b2b[j];
#pragma unroll
    for (int n = 0; n < NPB; n++) {
        if (n < nvalid) out[(long)(nbase + n) * DO + j] = acc2[n] + bb;
    }
}

// ---------------------------------------------------------------------------
extern "C" void kernel_launch(void* const* d_in, const int* in_sizes, int n_in,
                              void* d_out, int out_size, void* d_ws, size_t ws_size,
                              hipStream_t stream)
{
    // setup_inputs order (17 entries):
    // 0:x 1:edge_index 2:edge_attr 3:u 4:batch
    // 5:W1a 6:b1a 7:g1 8:be1 9:W1b 10:b1b
    // 11:W2a 12:b2a 13:g2 14:be2 15:W2b 16:b2b
    const float* x          = (const float*)d_in[0];
    const int*   edge_index = (const int*)d_in[1];
    const float* edge_attr  = (const float*)d_in[2];
    const float* u          = (const float*)d_in[3];
    // d_in[4] = batch (unused: single graph)
    const float* W1a = (const float*)d_in[5];
    const float* b1a = (const float*)d_in[6];
    const float* g1  = (const float*)d_in[7];
    const float* be1 = (const float*)d_in[8];
    const float* W1b = (const float*)d_in[9];
    const float* b1b = (const float*)d_in[10];
    const float* W2a = (const float*)d_in[11];
    const float* b2a = (const float*)d_in[12];
    const float* g2  = (const float*)d_in[13];
    const float* be2 = (const float*)d_in[14];
    const float* W2b = (const float*)d_in[15];
    const float* b2b = (const float*)d_in[16];

    const int N = in_sizes[0] / DN;          // 50000
    const int E = in_sizes[2] / DE;          // 800000
    float* out  = (float*)d_out;
    float* sums = (float*)d_ws;              // [N, DO]
    float* cnt  = sums + (size_t)N * DO;     // [N]

    // Zero the scatter accumulators (ws is poisoned 0xAA before every launch)
    (void)hipMemsetAsync(d_ws, 0, ((size_t)N * DO + N) * sizeof(float), stream);

    const int eblocks = (E + EPB - 1) / EPB;
    edge_kernel<<<eblocks, 128, 0, stream>>>(
        x, edge_index, edge_attr, u, W1a, b1a, g1, be1, W1b, b1b, sums, cnt, E);

    const int nblocks = (N + NPB - 1) / NPB;
    node_kernel<<<nblocks, 128, 0, stream>>>(
        x, sums, cnt, W2a, b2a, g2, be2, W2b, b2b, out, N);
}

// Round 4
// 833.930 us; speedup vs baseline: 2.7364x; 2.7364x over previous
//
#include <hip/hip_runtime.h>
#include <hip/hip_bf16.h>

// Problem constants
constexpr int DN = 128, DE = 64, DG = 32, DO = 128;
constexpr int K1 = DN + DE + DG;  // 224
constexpr int K2 = DN + DO;       // 256
constexpr float NEG_SLOPE = 0.01f;
constexpr float LN_EPS = 1e-5f;

constexpr int EPB = 128;   // edges per block (MFMA edge kernel)
constexpr int NPB = 8;     // nodes per block
constexpr int A_LD = 40;   // LDS row stride in shorts (32 + 8 pad)

typedef __attribute__((ext_vector_type(8))) short bf16x8;
typedef __attribute__((ext_vector_type(4))) float f32x4;

__device__ inline unsigned short f2bf(float f) {
    // round-to-nearest-even fp32 -> bf16
    unsigned u = __builtin_bit_cast(unsigned, f);
    u += 0x7FFFu + ((u >> 16) & 1u);
    return (unsigned short)(u >> 16);
}

// ---------------------------------------------------------------------------
// Edge kernel (MFMA): h1 = concat(x[src], edge_attr, u) @ W1a  (bf16 MFMA)
// h = LN(leaky(h1 + b1a)); atomic scatter-add h into sums[dest], cnt[dest]++
// W1b is applied per-NODE later:  sum(h2) = sum(h)@W1b + cnt*b1b.
// Block: 256 threads (4 waves). Wave w owns edges [32w,32w+32); per wave:
// 2 Mtiles x 8 Ntiles of mfma_f32_16x16x32_bf16; K=224 in 7 slabs of 32.
// B slab is converted f32->bf16 from W1a on the fly (W1a is L2-resident).
// ---------------------------------------------------------------------------
__global__ __launch_bounds__(256) void edge_kernel(
    const float* __restrict__ x, const int* __restrict__ edge_index,
    const float* __restrict__ edge_attr, const float* __restrict__ u,
    const float* __restrict__ W1a,
    const float* __restrict__ b1a, const float* __restrict__ g1,
    const float* __restrict__ be1,
    float* __restrict__ sums, float* __restrict__ cnt, int E)
{
    __shared__ unsigned short s_a[EPB * A_LD];   // A slab: [128 edges][32 k] bf16
    __shared__ unsigned short s_b[128 * A_LD];   // B slab: [128 n][32 k] bf16 (W1a^T)
    __shared__ int s_src[EPB], s_dst[EPB];

    const int tid  = threadIdx.x;
    const int lane = tid & 63, wave = tid >> 6;
    const int l15  = lane & 15, quad = lane >> 4;
    const int ebase  = blockIdx.x * EPB;
    const int evalid = min(EPB, E - ebase);

    if (tid < EPB) {
        int e = ebase + tid;
        bool v = tid < evalid;
        s_src[tid] = v ? edge_index[e] : 0;
        s_dst[tid] = v ? edge_index[E + e] : 0;
    }
    __syncthreads();

    f32x4 acc[2][8];
#pragma unroll
    for (int mt = 0; mt < 2; ++mt)
#pragma unroll
        for (int nt = 0; nt < 8; ++nt) acc[mt][nt] = (f32x4){0.f, 0.f, 0.f, 0.f};

    const int e0 = tid >> 3;        // 0..31
    const int k4 = (tid & 7) * 4;   // 0,4,..,28

    for (int ks = 0; ks < 7; ++ks) {
        const int kbase = ks * 32;
        // ---- stage A slab: gather + fp32->bf16 convert ----
#pragma unroll
        for (int it = 0; it < 4; ++it) {
            int e = e0 + it * 32;
            float4 v;
            if (ks < 4) {
                v = *(const float4*)&x[(long)s_src[e] * DN + kbase + k4];
            } else if (ks < 6) {
                long row = min((long)(ebase + e), (long)E - 1);
                v = *(const float4*)&edge_attr[row * DE + (kbase - DN) + k4];
            } else {
                v = *(const float4*)&u[k4];
            }
            ushort4 b;
            b.x = f2bf(v.x); b.y = f2bf(v.y); b.z = f2bf(v.z); b.w = f2bf(v.w);
            *(ushort4*)&s_a[e * A_LD + k4] = b;
        }
        // ---- stage B slab: W1a[k][n] f32 -> s_b[n][k] bf16, packed b32 ----
        // p in [0,2048): k2 = k-pair index (0..15), n = 0..127
#pragma unroll
        for (int it = 0; it < 8; ++it) {
            int p = tid + it * 256;
            int k2 = p >> 7, n = p & 127;
            float w0 = W1a[(long)(kbase + 2 * k2) * DO + n];
            float w1 = W1a[(long)(kbase + 2 * k2 + 1) * DO + n];
            unsigned pk = (unsigned)f2bf(w0) | ((unsigned)f2bf(w1) << 16);
            *(unsigned*)&s_b[n * A_LD + 2 * k2] = pk;
        }
        __syncthreads();
        // ---- MFMA: 2 Mtiles x 8 Ntiles ----
        bf16x8 a0 = *(const bf16x8*)&s_a[(wave * 32 + l15) * A_LD + quad * 8];
        bf16x8 a1 = *(const bf16x8*)&s_a[(wave * 32 + 16 + l15) * A_LD + quad * 8];
#pragma unroll
        for (int nt = 0; nt < 8; ++nt) {
            bf16x8 b = *(const bf16x8*)&s_b[(nt * 16 + l15) * A_LD + quad * 8];
            acc[0][nt] = __builtin_amdgcn_mfma_f32_16x16x32_bf16(a0, b, acc[0][nt], 0, 0, 0);
            acc[1][nt] = __builtin_amdgcn_mfma_f32_16x16x32_bf16(a1, b, acc[1][nt], 0, 0, 0);
        }
        __syncthreads();
    }

    // ---- bias + LeakyReLU + LayerNorm + scatter ----
    // C layout: col = nt*16 + l15, local row = wave*32 + mt*16 + quad*4 + reg
    float ba[8], gg[8], bb[8];
#pragma unroll
    for (int nt = 0; nt < 8; ++nt) {
        int col = nt * 16 + l15;
        ba[nt] = b1a[col]; gg[nt] = g1[col]; bb[nt] = be1[col];
    }
#pragma unroll
    for (int mt = 0; mt < 2; ++mt) {
#pragma unroll
        for (int r = 0; r < 4; ++r) {
            float v[8];
            float s = 0.f, q = 0.f;
#pragma unroll
            for (int nt = 0; nt < 8; ++nt) {
                float t = acc[mt][nt][r] + ba[nt];
                t = (t >= 0.f) ? t : NEG_SLOPE * t;
                v[nt] = t; s += t; q += t * t;
            }
            // reduce over the 16 lanes of each quad (cols of this row)
#pragma unroll
            for (int off = 1; off < 16; off <<= 1) {
                s += __shfl_xor(s, off, 64);
                q += __shfl_xor(q, off, 64);
            }
            float mu  = s * (1.f / DO);
            float var = q * (1.f / DO) - mu * mu;
            float rs  = rsqrtf(var + LN_EPS);
            int lrow = wave * 32 + mt * 16 + quad * 4 + r;
            if (lrow < evalid) {
                long base = (long)s_dst[lrow] * DO;
#pragma unroll
                for (int nt = 0; nt < 8; ++nt) {
                    float h = (v[nt] - mu) * rs * gg[nt] + bb[nt];
                    atomicAdd(&sums[base + nt * 16 + l15], h);
                }
            }
        }
    }
    if (tid < evalid) atomicAdd(&cnt[s_dst[tid]], 1.0f);
}

// ---------------------------------------------------------------------------
// Node kernel: agg = (sums[n]/max(cnt,1)) @ W1b + b1b*(cnt>0)
//              out = LN(leaky(concat(x,agg)@W2a+b2a)) @ W2b + b2b
// ---------------------------------------------------------------------------
__global__ __launch_bounds__(128) void node_kernel(
    const float* __restrict__ x, const float* __restrict__ sums,
    const float* __restrict__ cnt,
    const float* __restrict__ W1b, const float* __restrict__ b1b,
    const float* __restrict__ W2a, const float* __restrict__ b2a,
    const float* __restrict__ g2, const float* __restrict__ be2,
    const float* __restrict__ W2b, const float* __restrict__ b2b,
    float* __restrict__ out, int N)
{
    __shared__ float s_pre[NPB][DO];
    __shared__ float s_in[NPB][K2];
    __shared__ float s_hn[NPB][DO];
    __shared__ float s_red[2][2][NPB];
    __shared__ float s_cflag[NPB];

    const int tid = threadIdx.x;
    const int j = tid;
    const int lane = tid & 63;
    const int wave = tid >> 6;
    const int nbase = blockIdx.x * NPB;
    const int nvalid = min(NPB, N - nbase);

    // stage s_pre = sums/max(cnt,1);  s_in[:,0:128] = x
    for (int idx = tid; idx < NPB * DO; idx += 128) {
        int n = idx >> 7, k = idx & 127;
        float v = 0.f, xv = 0.f;
        if (n < nvalid) {
            int node = nbase + n;
            float c = cnt[node];
            if (k == 0) s_cflag[n] = (c > 0.f) ? 1.f : 0.f;
            c = (c > 1.f) ? c : 1.f;
            v  = sums[(long)node * DO + k] / c;
            xv = x[(long)node * DN + k];
        } else if (k == 0) {
            s_cflag[n] = 0.f;
        }
        s_pre[n][k] = v;
        s_in[n][k]  = xv;
    }
    __syncthreads();

    // GEMM0: agg = s_pre @ W1b (+ b1b if node had edges)
    {
        float aggv[NPB];
#pragma unroll
        for (int n = 0; n < NPB; n++) aggv[n] = 0.f;
        for (int kk = 0; kk < DO; kk += 4) {
            const float w0 = W1b[(kk + 0) * DO + j];
            const float w1 = W1b[(kk + 1) * DO + j];
            const float w2 = W1b[(kk + 2) * DO + j];
            const float w3 = W1b[(kk + 3) * DO + j];
#pragma unroll
            for (int n = 0; n < NPB; n++) {
                const float4 h = *reinterpret_cast<const float4*>(&s_pre[n][kk]);
                aggv[n] = fmaf(h.x, w0, fmaf(h.y, w1, fmaf(h.z, w2, fmaf(h.w, w3, aggv[n]))));
            }
        }
        const float b1 = b1b[j];
#pragma unroll
        for (int n = 0; n < NPB; n++) s_in[n][DN + j] = aggv[n] + s_cflag[n] * b1;
    }
    __syncthreads();

    // GEMM1: [NPB,256] @ W2a
    float acc[NPB];
#pragma unroll
    for (int n = 0; n < NPB; n++) acc[n] = 0.f;
    for (int kk = 0; kk < K2; kk += 4) {
        const float w0 = W2a[(kk + 0) * DO + j];
        const float w1 = W2a[(kk + 1) * DO + j];
        const float w2 = W2a[(kk + 2) * DO + j];
        const float w3 = W2a[(kk + 3) * DO + j];
#pragma unroll
        for (int n = 0; n < NPB; n++) {
            const float4 h = *reinterpret_cast<const float4*>(&s_in[n][kk]);
            acc[n] = fmaf(h.x, w0, fmaf(h.y, w1, fmaf(h.z, w2, fmaf(h.w, w3, acc[n]))));
        }
    }

    const float ba = b2a[j];
#pragma unroll
    for (int n = 0; n < NPB; n++) {
        float v = acc[n] + ba;
        acc[n] = (v >= 0.f) ? v : NEG_SLOPE * v;
    }

#pragma unroll
    for (int n = 0; n < NPB; n++) {
        float s = acc[n], s2 = acc[n] * acc[n];
        for (int off = 32; off; off >>= 1) {
            s += __shfl_down(s, off, 64);
            s2 += __shfl_down(s2, off, 64);
        }
        if (lane == 0) { s_red[wave][0][n] = s; s_red[wave][1][n] = s2; }
    }
    __syncthreads();

    const float g = g2[j], be = be2[j];
#pragma unroll
    for (int n = 0; n < NPB; n++) {
        float sum = s_red[0][0][n] + s_red[1][0][n];
        float sq  = s_red[0][1][n] + s_red[1][1][n];
        float mu = sum * (1.f / DO);
        float var = sq * (1.f / DO) - mu * mu;
        float rs = rsqrtf(var + LN_EPS);
        s_hn[n][j] = (acc[n] - mu) * rs * g + be;
    }
    __syncthreads();

    float acc2[NPB];
#pragma unroll
    for (int n = 0; n < NPB; n++) acc2[n] = 0.f;
    for (int kk = 0; kk < DO; kk += 4) {
        const float w0 = W2b[(kk + 0) * DO + j];
        const float w1 = W2b[(kk + 1) * DO + j];
        const float w2 = W2b[(kk + 2) * DO + j];
        const float w3 = W2b[(kk + 3) * DO + j];
#pragma unroll
        for (int n = 0; n < NPB; n++) {
            const float4 h = *reinterpret_cast<const float4*>(&s_hn[n][kk]);
            acc2[n] = fmaf(h.x, w0, fmaf(h.y, w1, fmaf(h.z, w2, fmaf(h.w, w3, acc2[n]))));
        }
    }

    const float bb = b2b[j];
#pragma unroll
    for (int n = 0; n < NPB; n++) {
        if (n < nvalid) out[(long)(nbase + n) * DO + j] = acc2[n] + bb;
    }
}

// ---------------------------------------------------------------------------
extern "C" void kernel_launch(void* const* d_in, const int* in_sizes, int n_in,
                              void* d_out, int out_size, void* d_ws, size_t ws_size,
                              hipStream_t stream)
{
    // 0:x 1:edge_index 2:edge_attr 3:u 4:batch
    // 5:W1a 6:b1a 7:g1 8:be1 9:W1b 10:b1b 11:W2a 12:b2a 13:g2 14:be2 15:W2b 16:b2b
    const float* x          = (const float*)d_in[0];
    const int*   edge_index = (const int*)d_in[1];
    const float* edge_attr  = (const float*)d_in[2];
    const float* u          = (const float*)d_in[3];
    const float* W1a = (const float*)d_in[5];
    const float* b1a = (const float*)d_in[6];
    const float* g1  = (const float*)d_in[7];
    const float* be1 = (const float*)d_in[8];
    const float* W1b = (const float*)d_in[9];
    const float* b1b = (const float*)d_in[10];
    const float* W2a = (const float*)d_in[11];
    const float* b2a = (const float*)d_in[12];
    const float* g2  = (const float*)d_in[13];
    const float* be2 = (const float*)d_in[14];
    const float* W2b = (const float*)d_in[15];
    const float* b2b = (const float*)d_in[16];

    const int N = in_sizes[0] / DN;   // 50000
    const int E = in_sizes[2] / DE;   // 800000
    float* out  = (float*)d_out;

    // Workspace: sums [N*DO] f32 | cnt [N] f32   (same footprint as the
    // proven R2 layout — no extra scratch)
    float* sums = (float*)d_ws;
    float* cnt  = sums + (size_t)N * DO;

    (void)hipMemsetAsync(d_ws, 0, ((size_t)N * DO + N) * sizeof(float), stream);

    const int eblocks = (E + EPB - 1) / EPB;
    edge_kernel<<<eblocks, 256, 0, stream>>>(
        x, edge_index, edge_attr, u, W1a, b1a, g1, be1, sums, cnt, E);

    const int nblocks = (N + NPB - 1) / NPB;
    node_kernel<<<nblocks, 128, 0, stream>>>(
        x, sums, cnt, W1b, b1b, W2a, b2a, g2, be2, W2b, b2b, out, N);
}

// Round 5
// 740.808 us; speedup vs baseline: 3.0804x; 1.1257x over previous
//
#include <hip/hip_runtime.h>
#include <hip/hip_fp16.h>
#include <hip/hip_bf16.h>

// Problem constants
constexpr int DN = 128, DE = 64, DG = 32, DO = 128;
constexpr int K1 = DN + DE + DG;  // 224
constexpr int K2 = DN + DO;       // 256
constexpr float NEG_SLOPE = 0.01f;
constexpr float LN_EPS = 1e-5f;

constexpr int EPB = 128;   // edges per block (edge kernel)
constexpr int NB  = 64;    // nodes per block (node kernel)
constexpr int A_LD = 40;   // edge LDS row stride in shorts (32 + 8 pad)
constexpr int B_LD = 40;   // B-slab row stride in shorts
constexpr int H_LD = 264;  // node s_h row stride in shorts (256 + 8 pad; 528B = 33*16 keeps 16B alignment)

typedef __attribute__((ext_vector_type(8))) short bf16x8;
typedef __attribute__((ext_vector_type(4))) float f32x4;

__device__ inline unsigned short f2bf(float f) {
    unsigned u = __builtin_bit_cast(unsigned, f);
    u += 0x7FFFu + ((u >> 16) & 1u);
    return (unsigned short)(u >> 16);
}

// ---------------------------------------------------------------------------
// Edge kernel (MFMA): h1 = concat(x[src], edge_attr, u) @ W1a  (bf16 MFMA)
// h = LN(leaky(h1 + b1a)); scatter-add h into sums[dest] (packed f16 atomics),
// cnt[dest]++.  W1b applied per-node later: sum(h2) = sum(h)@W1b + cnt*b1b.
// ---------------------------------------------------------------------------
__global__ __launch_bounds__(256) void edge_kernel(
    const float* __restrict__ x, const int* __restrict__ edge_index,
    const float* __restrict__ edge_attr, const float* __restrict__ u,
    const float* __restrict__ W1a,
    const float* __restrict__ b1a, const float* __restrict__ g1,
    const float* __restrict__ be1,
    __half* __restrict__ sums, float* __restrict__ cnt, int E)
{
    __shared__ unsigned short s_a[EPB * A_LD];
    __shared__ unsigned short s_b[128 * B_LD];
    __shared__ int s_src[EPB], s_dst[EPB];

    const int tid  = threadIdx.x;
    const int lane = tid & 63, wave = tid >> 6;
    const int l15  = lane & 15, quad = lane >> 4;
    const int ebase  = blockIdx.x * EPB;
    const int evalid = min(EPB, E - ebase);

    if (tid < EPB) {
        int e = ebase + tid;
        bool v = tid < evalid;
        s_src[tid] = v ? edge_index[e] : 0;
        s_dst[tid] = v ? edge_index[E + e] : 0;
    }
    __syncthreads();

    f32x4 acc[2][8];
#pragma unroll
    for (int mt = 0; mt < 2; ++mt)
#pragma unroll
        for (int nt = 0; nt < 8; ++nt) acc[mt][nt] = (f32x4){0.f, 0.f, 0.f, 0.f};

    const int e0 = tid >> 3;        // 0..31
    const int k4 = (tid & 7) * 4;   // 0,4,..,28

    for (int ks = 0; ks < 7; ++ks) {
        const int kbase = ks * 32;
        // A slab: gather + f32->bf16
#pragma unroll
        for (int it = 0; it < 4; ++it) {
            int e = e0 + it * 32;
            float4 v;
            if (ks < 4) {
                v = *(const float4*)&x[(long)s_src[e] * DN + kbase + k4];
            } else if (ks < 6) {
                long row = min((long)(ebase + e), (long)E - 1);
                v = *(const float4*)&edge_attr[row * DE + (kbase - DN) + k4];
            } else {
                v = *(const float4*)&u[k4];
            }
            ushort4 b;
            b.x = f2bf(v.x); b.y = f2bf(v.y); b.z = f2bf(v.z); b.w = f2bf(v.w);
            *(ushort4*)&s_a[e * A_LD + k4] = b;
        }
        // B slab: W1a[k][n] f32 -> s_b[n][k] bf16 (packed b32 writes)
#pragma unroll
        for (int it = 0; it < 8; ++it) {
            int p = tid + it * 256;
            int k2 = p >> 7, n = p & 127;
            float w0 = W1a[(long)(kbase + 2 * k2) * DO + n];
            float w1 = W1a[(long)(kbase + 2 * k2 + 1) * DO + n];
            unsigned pk = (unsigned)f2bf(w0) | ((unsigned)f2bf(w1) << 16);
            *(unsigned*)&s_b[n * B_LD + 2 * k2] = pk;
        }
        __syncthreads();
        bf16x8 a0 = *(const bf16x8*)&s_a[(wave * 32 + l15) * A_LD + quad * 8];
        bf16x8 a1 = *(const bf16x8*)&s_a[(wave * 32 + 16 + l15) * A_LD + quad * 8];
#pragma unroll
        for (int nt = 0; nt < 8; ++nt) {
            bf16x8 b = *(const bf16x8*)&s_b[(nt * 16 + l15) * B_LD + quad * 8];
            acc[0][nt] = __builtin_amdgcn_mfma_f32_16x16x32_bf16(a0, b, acc[0][nt], 0, 0, 0);
            acc[1][nt] = __builtin_amdgcn_mfma_f32_16x16x32_bf16(a1, b, acc[1][nt], 0, 0, 0);
        }
        __syncthreads();
    }

    // bias + LeakyReLU + LayerNorm + packed-f16 atomic scatter
    float ba[8], gg[8], bb[8];
#pragma unroll
    for (int nt = 0; nt < 8; ++nt) {
        int col = nt * 16 + l15;
        ba[nt] = b1a[col]; gg[nt] = g1[col]; bb[nt] = be1[col];
    }
#pragma unroll
    for (int mt = 0; mt < 2; ++mt) {
#pragma unroll
        for (int r = 0; r < 4; ++r) {
            float v[8];
            float s = 0.f, q = 0.f;
#pragma unroll
            for (int nt = 0; nt < 8; ++nt) {
                float t = acc[mt][nt][r] + ba[nt];
                t = (t >= 0.f) ? t : NEG_SLOPE * t;
                v[nt] = t; s += t; q += t * t;
            }
#pragma unroll
            for (int off = 1; off < 16; off <<= 1) {
                s += __shfl_xor(s, off, 64);
                q += __shfl_xor(q, off, 64);
            }
            float mu  = s * (1.f / DO);
            float var = q * (1.f / DO) - mu * mu;
            float rs  = rsqrtf(var + LN_EPS);
            int lrow = wave * 32 + mt * 16 + quad * 4 + r;
            bool doat = (lrow < evalid);
            long base = (long)s_dst[lrow] * DO;
#pragma unroll
            for (int nt = 0; nt < 8; ++nt) {
                float h  = (v[nt] - mu) * rs * gg[nt] + bb[nt];
                float hp = __shfl_xor(h, 1, 64);    // partner col (l15^1)
                if (doat && ((l15 & 1) == 0)) {
                    __half2 pv = __halves2half2(__float2half_rn(h),
                                                __float2half_rn(hp));
                    unsafeAtomicAdd((__half2*)&sums[base + nt * 16 + l15], pv);
                }
            }
        }
    }
    if (tid < evalid) atomicAdd(&cnt[s_dst[tid]], 1.0f);
}

// ---------------------------------------------------------------------------
// Node kernel (MFMA): agg = (sums/max(cnt,1)) @ W1b + (cnt>0)*b1b
//   out = LN(leaky(concat(x,agg) @ W2a + b2a)) @ W2b + b2b
// Block: 256 thr / 4 waves, 64 nodes. Wave w owns rows [16w,16w+16).
// A operands live in s_h [64][256+pad] bf16; B slabs staged f32->bf16.
// ---------------------------------------------------------------------------
__global__ __launch_bounds__(256) void node_kernel(
    const float* __restrict__ x, const __half* __restrict__ sums,
    const float* __restrict__ cnt,
    const float* __restrict__ W1b, const float* __restrict__ b1b,
    const float* __restrict__ W2a, const float* __restrict__ b2a,
    const float* __restrict__ g2, const float* __restrict__ be2,
    const float* __restrict__ W2b, const float* __restrict__ b2b,
    float* __restrict__ out, int N)
{
    __shared__ unsigned short s_h[NB * H_LD];
    __shared__ unsigned short s_b[128 * B_LD];
    __shared__ float s_cf[NB];

    const int tid  = threadIdx.x;
    const int lane = tid & 63, wave = tid >> 6;
    const int l15  = lane & 15, quad = lane >> 4;
    const int nbase  = blockIdx.x * NB;
    const int nvalid = min(NB, N - nbase);

    // ---- stage x (cols 0..127) + pre = sums/max(cnt,1) (cols 128..255) ----
#pragma unroll
    for (int i = 0; i < 8; ++i) {
        int p = tid + i * 256;              // [0,2048) float4 chunks
        int row = p >> 5, c4 = (p & 31) * 4;
        int node = nbase + min(row, nvalid - 1);
        float4 v = *(const float4*)&x[(long)node * DN + c4];
        ushort4 b;
        b.x = f2bf(v.x); b.y = f2bf(v.y); b.z = f2bf(v.z); b.w = f2bf(v.w);
        *(ushort4*)&s_h[row * H_LD + c4] = b;
    }
#pragma unroll
    for (int i = 0; i < 8; ++i) {
        int p = tid + i * 256;              // [0,2048) 4-half chunks
        int row = p >> 5, c = (p & 31) * 4;
        int node = nbase + min(row, nvalid - 1);
        float cn = cnt[node];
        if (c == 0) s_cf[row] = (cn > 0.f) ? 1.f : 0.f;
        float inv = 1.f / fmaxf(cn, 1.f);
        const __half2* sp = (const __half2*)&sums[(long)node * DO + c];
        float2 a0 = __half22float2(sp[0]);
        float2 a1 = __half22float2(sp[1]);
        ushort4 b;
        b.x = f2bf(a0.x * inv); b.y = f2bf(a0.y * inv);
        b.z = f2bf(a1.x * inv); b.w = f2bf(a1.y * inv);
        *(ushort4*)&s_h[row * H_LD + DN + c] = b;
    }

    const unsigned short* aPtr = &s_h[(wave * 16 + l15) * H_LD];

    f32x4 acc[8];

    // ===== GEMM0: agg = pre @ W1b  (K=128, 4 slabs) =====
#pragma unroll
    for (int nt = 0; nt < 8; ++nt) acc[nt] = (f32x4){0.f, 0.f, 0.f, 0.f};
    for (int ks = 0; ks < 4; ++ks) {
        __syncthreads();
#pragma unroll
        for (int it = 0; it < 8; ++it) {
            int p = tid + it * 256;
            int k2 = p >> 7, n = p & 127;
            float w0 = W1b[(long)(ks * 32 + 2 * k2) * DO + n];
            float w1 = W1b[(long)(ks * 32 + 2 * k2 + 1) * DO + n];
            unsigned pk = (unsigned)f2bf(w0) | ((unsigned)f2bf(w1) << 16);
            *(unsigned*)&s_b[n * B_LD + 2 * k2] = pk;
        }
        __syncthreads();
        bf16x8 a = *(const bf16x8*)&aPtr[DN + ks * 32 + quad * 8];
#pragma unroll
        for (int nt = 0; nt < 8; ++nt) {
            bf16x8 b = *(const bf16x8*)&s_b[(nt * 16 + l15) * B_LD + quad * 8];
            acc[nt] = __builtin_amdgcn_mfma_f32_16x16x32_bf16(a, b, acc[nt], 0, 0, 0);
        }
    }
    // agg + cf*b1b -> bf16 -> s_h cols [128,256)
    __syncthreads();
    {
        float b1v[8];
#pragma unroll
        for (int nt = 0; nt < 8; ++nt) b1v[nt] = b1b[nt * 16 + l15];
#pragma unroll
        for (int reg = 0; reg < 4; ++reg) {
            int row = wave * 16 + quad * 4 + reg;
            float cf = s_cf[row];
#pragma unroll
            for (int nt = 0; nt < 8; ++nt) {
                float v = acc[nt][reg] + cf * b1v[nt];
                s_h[row * H_LD + DN + nt * 16 + l15] = f2bf(v);
            }
        }
    }

    // ===== GEMM1: t = concat(x,agg) @ W2a  (K=256, 8 slabs) =====
#pragma unroll
    for (int nt = 0; nt < 8; ++nt) acc[nt] = (f32x4){0.f, 0.f, 0.f, 0.f};
    for (int ks = 0; ks < 8; ++ks) {
        __syncthreads();
#pragma unroll
        for (int it = 0; it < 8; ++it) {
            int p = tid + it * 256;
            int k2 = p >> 7, n = p & 127;
            float w0 = W2a[(long)(ks * 32 + 2 * k2) * DO + n];
            float w1 = W2a[(long)(ks * 32 + 2 * k2 + 1) * DO + n];
            unsigned pk = (unsigned)f2bf(w0) | ((unsigned)f2bf(w1) << 16);
            *(unsigned*)&s_b[n * B_LD + 2 * k2] = pk;
        }
        __syncthreads();
        bf16x8 a = *(const bf16x8*)&aPtr[ks * 32 + quad * 8];
#pragma unroll
        for (int nt = 0; nt < 8; ++nt) {
            bf16x8 b = *(const bf16x8*)&s_b[(nt * 16 + l15) * B_LD + quad * 8];
            acc[nt] = __builtin_amdgcn_mfma_f32_16x16x32_bf16(a, b, acc[nt], 0, 0, 0);
        }
    }
    // bias + leaky + LN -> hn bf16 -> s_h cols [0,128)
    __syncthreads();
    {
        float ba[8], gg[8], bb[8];
#pragma unroll
        for (int nt = 0; nt < 8; ++nt) {
            int col = nt * 16 + l15;
            ba[nt] = b2a[col]; gg[nt] = g2[col]; bb[nt] = be2[col];
        }
#pragma unroll
        for (int reg = 0; reg < 4; ++reg) {
            float v[8];
            float s = 0.f, q = 0.f;
#pragma unroll
            for (int nt = 0; nt < 8; ++nt) {
                float t = acc[nt][reg] + ba[nt];
                t = (t >= 0.f) ? t : NEG_SLOPE * t;
                v[nt] = t; s += t; q += t * t;
            }
#pragma unroll
            for (int off = 1; off < 16; off <<= 1) {
                s += __shfl_xor(s, off, 64);
                q += __shfl_xor(q, off, 64);
            }
            float mu  = s * (1.f / DO);
            float var = q * (1.f / DO) - mu * mu;
            float rs  = rsqrtf(var + LN_EPS);
            int row = wave * 16 + quad * 4 + reg;
#pragma unroll
            for (int nt = 0; nt < 8; ++nt) {
                float h = (v[nt] - mu) * rs * gg[nt] + bb[nt];
                s_h[row * H_LD + nt * 16 + l15] = f2bf(h);
            }
        }
    }

    // ===== GEMM2: out = hn @ W2b + b2b  (K=128, 4 slabs) =====
#pragma unroll
    for (int nt = 0; nt < 8; ++nt) acc[nt] = (f32x4){0.f, 0.f, 0.f, 0.f};
    for (int ks = 0; ks < 4; ++ks) {
        __syncthreads();
#pragma unroll
        for (int it = 0; it < 8; ++it) {
            int p = tid + it * 256;
            int k2 = p >> 7, n = p & 127;
            float w0 = W2b[(long)(ks * 32 + 2 * k2) * DO + n];
            float w1 = W2b[(long)(ks * 32 + 2 * k2 + 1) * DO + n];
            unsigned pk = (unsigned)f2bf(w0) | ((unsigned)f2bf(w1) << 16);
            *(unsigned*)&s_b[n * B_LD + 2 * k2] = pk;
        }
        __syncthreads();
        bf16x8 a = *(const bf16x8*)&aPtr[ks * 32 + quad * 8];
#pragma unroll
        for (int nt = 0; nt < 8; ++nt) {
            bf16x8 b = *(const bf16x8*)&s_b[(nt * 16 + l15) * B_LD + quad * 8];
            acc[nt] = __builtin_amdgcn_mfma_f32_16x16x32_bf16(a, b, acc[nt], 0, 0, 0);
        }
    }
    {
        float b2v[8];
#pragma unroll
        for (int nt = 0; nt < 8; ++nt) b2v[nt] = b2b[nt * 16 + l15];
#pragma unroll
        for (int reg = 0; reg < 4; ++reg) {
            int row = wave * 16 + quad * 4 + reg;
            if (row < nvalid) {
                long base = (long)(nbase + row) * DO;
#pragma unroll
                for (int nt = 0; nt < 8; ++nt)
                    out[base + nt * 16 + l15] = acc[nt][reg] + b2v[nt];
            }
        }
    }
}

// ---------------------------------------------------------------------------
extern "C" void kernel_launch(void* const* d_in, const int* in_sizes, int n_in,
                              void* d_out, int out_size, void* d_ws, size_t ws_size,
                              hipStream_t stream)
{
    const float* x          = (const float*)d_in[0];
    const int*   edge_index = (const int*)d_in[1];
    const float* edge_attr  = (const float*)d_in[2];
    const float* u          = (const float*)d_in[3];
    const float* W1a = (const float*)d_in[5];
    const float* b1a = (const float*)d_in[6];
    const float* g1  = (const float*)d_in[7];
    const float* be1 = (const float*)d_in[8];
    const float* W1b = (const float*)d_in[9];
    const float* b1b = (const float*)d_in[10];
    const float* W2a = (const float*)d_in[11];
    const float* b2a = (const float*)d_in[12];
    const float* g2  = (const float*)d_in[13];
    const float* be2 = (const float*)d_in[14];
    const float* W2b = (const float*)d_in[15];
    const float* b2b = (const float*)d_in[16];

    const int N = in_sizes[0] / DN;   // 50000
    const int E = in_sizes[2] / DE;   // 800000
    float* out  = (float*)d_out;

    // Workspace: sums [N*DO] f16 | cnt [N] f32  (13 MB, well under R2's 25.8 MB)
    __half* sums = (__half*)d_ws;
    float*  cnt  = (float*)(sums + (size_t)N * DO);

    (void)hipMemsetAsync(d_ws, 0,
                         (size_t)N * DO * sizeof(__half) + (size_t)N * sizeof(float),
                         stream);

    const int eblocks = (E + EPB - 1) / EPB;
    edge_kernel<<<eblocks, 256, 0, stream>>>(
        x, edge_index, edge_attr, u, W1a, b1a, g1, be1, sums, cnt, E);

    const int nblocks = (N + NB - 1) / NB;
    node_kernel<<<nblocks, 256, 0, stream>>>(
        x, sums, cnt, W1b, b1b, W2a, b2a, g2, be2, W2b, b2b, out, N);
}

// Round 6
// 711.488 us; speedup vs baseline: 3.2073x; 1.0412x over previous
//
#include <hip/hip_runtime.h>
#include <hip/hip_fp16.h>
#include <hip/hip_bf16.h>

// Problem constants
constexpr int DN = 128, DE = 64, DG = 32, DO = 128;
constexpr int K1 = DN + DE + DG;  // 224
constexpr float NEG_SLOPE = 0.01f;
constexpr float LN_EPS = 1e-5f;

constexpr int EPB = 128;   // edges per block (4 waves x 32 edges)
constexpr int NB  = 64;    // nodes per block (4 waves x 16 nodes)
constexpr int T_LD = 136;  // node per-wave LDS row stride in shorts (272B = 17*16)

typedef __attribute__((ext_vector_type(8))) short bf16x8;
typedef __attribute__((ext_vector_type(4))) float f32x4;

__device__ inline unsigned short f2bf(float f) {
    unsigned u = __builtin_bit_cast(unsigned, f);
    u += 0x7FFFu + ((u >> 16) & 1u);
    return (unsigned short)(u >> 16);
}

__device__ inline bf16x8 pk8(float4 p, float4 q) {
    bf16x8 r;
    r[0] = (short)f2bf(p.x); r[1] = (short)f2bf(p.y);
    r[2] = (short)f2bf(p.z); r[3] = (short)f2bf(p.w);
    r[4] = (short)f2bf(q.x); r[5] = (short)f2bf(q.y);
    r[6] = (short)f2bf(q.z); r[7] = (short)f2bf(q.w);
    return r;
}

// ---------------------------------------------------------------------------
// Weight prep: build fragment-ordered bf16 tables for W1a/W1b/W2a/W2b.
// Fragment-lane idx -> 8 bf16 (16B). B-frag layout for mfma_f32_16x16x32_bf16:
//   B[n = nt*16 + (lane&15)][k = ks*32 + (lane>>4)*8 + j]
// Table entry: tab[(base + (ks*8+nt)*64 + lane)*8 + j]
// Bases (in 8-short units): W1a=0 (7 slabs), W1b=7*512, W2a=11*512, W2b=19*512.
// ---------------------------------------------------------------------------
__global__ void wprep_kernel(const float* __restrict__ W1a,
                             const float* __restrict__ W1b,
                             const float* __restrict__ W2a,
                             const float* __restrict__ W2b,
                             unsigned short* __restrict__ tab) {
    int idx = blockIdx.x * 256 + threadIdx.x;   // fragment-lane id
    if (idx >= 23 * 512) return;
    int slabset = idx >> 9;        // 0..22
    int rem = idx & 511;           // nt*64 + lane
    const float* W; int sl;
    if (slabset < 7)       { W = W1a; sl = slabset; }
    else if (slabset < 11) { W = W1b; sl = slabset - 7; }
    else if (slabset < 19) { W = W2a; sl = slabset - 11; }
    else                   { W = W2b; sl = slabset - 19; }
    int nt = rem >> 6, lane = rem & 63;
    int quad = lane >> 4, l15 = lane & 15;
    int n = nt * 16 + l15;
    int k0 = sl * 32 + quad * 8;
    union { ushort4 u4[2]; unsigned short s[8]; } o;
#pragma unroll
    for (int j = 0; j < 8; ++j) o.s[j] = f2bf(W[(long)(k0 + j) * DO + n]);
    *(ushort4*)&tab[(long)idx * 8]     = o.u4[0];
    *(ushort4*)&tab[(long)idx * 8 + 4] = o.u4[1];
}

// ---------------------------------------------------------------------------
// Edge kernel: h1 = concat(x[src], edge_attr, u) @ W1a  (bf16 MFMA, direct
// register fragments — no LDS staging, no K-loop barriers)
// h = LN(leaky(h1+b1a)); scatter packed-f16 atomics into sums[dest]; cnt++.
// ---------------------------------------------------------------------------
__global__ __launch_bounds__(256) void edge_kernel(
    const float* __restrict__ x, const int* __restrict__ edge_index,
    const float* __restrict__ edge_attr, const float* __restrict__ u,
    const unsigned short* __restrict__ tab,
    const float* __restrict__ b1a, const float* __restrict__ g1,
    const float* __restrict__ be1,
    __half* __restrict__ sums, float* __restrict__ cnt, int E)
{
    __shared__ int s_src[EPB], s_dst[EPB];

    const int tid = threadIdx.x, lane = tid & 63, wave = tid >> 6;
    const int l15 = lane & 15, quad = lane >> 4;
    const int ebase = blockIdx.x * EPB;
    const int evalid = min(EPB, E - ebase);

    if (tid < EPB) {
        int e = ebase + tid; bool v = tid < evalid;
        s_src[tid] = v ? edge_index[e] : 0;
        s_dst[tid] = v ? edge_index[E + e] : 0;
    }
    __syncthreads();

    const int r0 = wave * 32 + l15, r1 = r0 + 16;
    const long xs0 = (long)s_src[r0] * DN;
    const long xs1 = (long)s_src[r1] * DN;
    const long er0 = (long)min(ebase + r0, E - 1) * DE;
    const long er1 = (long)min(ebase + r1, E - 1) * DE;
    const bf16x8* tW1a = (const bf16x8*)tab;   // base 0, 7 slabs
    const int kq = quad * 8;

    f32x4 acc[2][8];
#pragma unroll
    for (int mt = 0; mt < 2; ++mt)
#pragma unroll
        for (int nt = 0; nt < 8; ++nt) acc[mt][nt] = (f32x4){0.f, 0.f, 0.f, 0.f};

#pragma unroll
    for (int ks = 0; ks < 7; ++ks) {
        float4 p0, q0, p1, q1;
        if (ks < 4) {
            const float* b0 = &x[xs0 + ks * 32 + kq];
            const float* b1 = &x[xs1 + ks * 32 + kq];
            p0 = *(const float4*)b0; q0 = *(const float4*)(b0 + 4);
            p1 = *(const float4*)b1; q1 = *(const float4*)(b1 + 4);
        } else if (ks < 6) {
            int c = ks * 32 - DN + kq;
            const float* b0 = &edge_attr[er0 + c];
            const float* b1 = &edge_attr[er1 + c];
            p0 = *(const float4*)b0; q0 = *(const float4*)(b0 + 4);
            p1 = *(const float4*)b1; q1 = *(const float4*)(b1 + 4);
        } else {
            p0 = *(const float4*)&u[kq]; q0 = *(const float4*)&u[kq + 4];
            p1 = p0; q1 = q0;
        }
        bf16x8 a0 = pk8(p0, q0);
        bf16x8 a1 = pk8(p1, q1);
#pragma unroll
        for (int nt = 0; nt < 8; ++nt) {
            bf16x8 b = tW1a[(ks * 8 + nt) * 64 + lane];
            acc[0][nt] = __builtin_amdgcn_mfma_f32_16x16x32_bf16(a0, b, acc[0][nt], 0, 0, 0);
            acc[1][nt] = __builtin_amdgcn_mfma_f32_16x16x32_bf16(a1, b, acc[1][nt], 0, 0, 0);
        }
    }

    // bias + LeakyReLU + LayerNorm + packed-f16 atomic scatter
    float ba[8], gg[8], bb[8];
#pragma unroll
    for (int nt = 0; nt < 8; ++nt) {
        int col = nt * 16 + l15;
        ba[nt] = b1a[col]; gg[nt] = g1[col]; bb[nt] = be1[col];
    }
#pragma unroll
    for (int mt = 0; mt < 2; ++mt) {
#pragma unroll
        for (int r = 0; r < 4; ++r) {
            float v[8];
            float s = 0.f, q = 0.f;
#pragma unroll
            for (int nt = 0; nt < 8; ++nt) {
                float t = acc[mt][nt][r] + ba[nt];
                t = (t >= 0.f) ? t : NEG_SLOPE * t;
                v[nt] = t; s += t; q += t * t;
            }
#pragma unroll
            for (int off = 1; off < 16; off <<= 1) {
                s += __shfl_xor(s, off, 64);
                q += __shfl_xor(q, off, 64);
            }
            float mu  = s * (1.f / DO);
            float var = q * (1.f / DO) - mu * mu;
            float rs  = rsqrtf(var + LN_EPS);
            int lrow = wave * 32 + mt * 16 + quad * 4 + r;
            bool doat = (lrow < evalid);
            long base = (long)s_dst[lrow] * DO;
#pragma unroll
            for (int nt = 0; nt < 8; ++nt) {
                float h  = (v[nt] - mu) * rs * gg[nt] + bb[nt];
                float hp = __shfl_xor(h, 1, 64);
                if (doat && ((l15 & 1) == 0)) {
                    __half2 pv = __halves2half2(__float2half_rn(h),
                                                __float2half_rn(hp));
                    unsafeAtomicAdd((__half2*)&sums[base + nt * 16 + l15], pv);
                }
            }
        }
    }
    if (tid < evalid) atomicAdd(&cnt[s_dst[tid]], 1.0f);
}

// ---------------------------------------------------------------------------
// Node kernel (wave-private, zero barriers):
//   agg = (sums/max(cnt,1)) @ W1b + (cnt>0)*b1b
//   out = LN(leaky(concat(x,agg) @ W2a + b2a)) @ W2b + b2b
// Each wave owns 16 nodes. agg/hn round-trip through a private LDS tile.
// All B fragments come straight from the bf16 fragment table (L2-resident).
// ---------------------------------------------------------------------------
__global__ __launch_bounds__(256) void node_kernel(
    const float* __restrict__ x, const __half* __restrict__ sums,
    const float* __restrict__ cnt, const unsigned short* __restrict__ tab,
    const float* __restrict__ b1b, const float* __restrict__ b2a,
    const float* __restrict__ g2, const float* __restrict__ be2,
    const float* __restrict__ b2b,
    float* __restrict__ out, int N)
{
    __shared__ unsigned short s_t[4][16 * T_LD];  // per-wave [16 rows][128 cols]

    const int tid = threadIdx.x, lane = tid & 63, wave = tid >> 6;
    const int l15 = lane & 15, quad = lane >> 4;
    const int nbase = blockIdx.x * NB;

    const bf16x8* tW1b = (const bf16x8*)tab + 7 * 512;
    const bf16x8* tW2a = (const bf16x8*)tab + 11 * 512;
    const bf16x8* tW2b = (const bf16x8*)tab + 19 * 512;

    // A-row node for this lane (rows are wave-local 0..15 = l15)
    const int nodeA = min(nbase + wave * 16 + l15, N - 1);
    const float invc = 1.f / fmaxf(cnt[nodeA], 1.f);
    const int kq = quad * 8;

    f32x4 acc[8];

    // ===== GEMM0: agg = pre @ W1b  (K=128, 4 slabs) =====
#pragma unroll
    for (int nt = 0; nt < 8; ++nt) acc[nt] = (f32x4){0.f, 0.f, 0.f, 0.f};
#pragma unroll
    for (int ks = 0; ks < 4; ++ks) {
        const __half2* sp = (const __half2*)(sums + (long)nodeA * DO + ks * 32 + kq);
        float2 f0 = __half22float2(sp[0]);
        float2 f1 = __half22float2(sp[1]);
        float2 f2 = __half22float2(sp[2]);
        float2 f3 = __half22float2(sp[3]);
        float4 p = {f0.x * invc, f0.y * invc, f1.x * invc, f1.y * invc};
        float4 q = {f2.x * invc, f2.y * invc, f3.x * invc, f3.y * invc};
        bf16x8 a = pk8(p, q);
#pragma unroll
        for (int nt = 0; nt < 8; ++nt) {
            bf16x8 b = tW1b[(ks * 8 + nt) * 64 + lane];
            acc[nt] = __builtin_amdgcn_mfma_f32_16x16x32_bf16(a, b, acc[nt], 0, 0, 0);
        }
    }
    // C rows (wave-local) = quad*4+reg; write agg to private tile as bf16
    {
#pragma unroll
        for (int reg = 0; reg < 4; ++reg) {
            int lrow = quad * 4 + reg;
            int nodeC = nbase + wave * 16 + lrow;
            float cf = (nodeC < N && cnt[min(nodeC, N - 1)] > 0.f) ? 1.f : 0.f;
#pragma unroll
            for (int nt = 0; nt < 8; ++nt) {
                float v = acc[nt][reg] + cf * b1b[nt * 16 + l15];
                s_t[wave][lrow * T_LD + nt * 16 + l15] = f2bf(v);
            }
        }
    }

    // ===== GEMM1: t = concat(x, agg) @ W2a  (K=256, 8 slabs) =====
#pragma unroll
    for (int nt = 0; nt < 8; ++nt) acc[nt] = (f32x4){0.f, 0.f, 0.f, 0.f};
#pragma unroll
    for (int ks = 0; ks < 8; ++ks) {
        bf16x8 a;
        if (ks < 4) {
            const float* b0 = &x[(long)nodeA * DN + ks * 32 + kq];
            a = pk8(*(const float4*)b0, *(const float4*)(b0 + 4));
        } else {
            a = *(const bf16x8*)&s_t[wave][l15 * T_LD + (ks - 4) * 32 + kq];
        }
#pragma unroll
        for (int nt = 0; nt < 8; ++nt) {
            bf16x8 b = tW2a[(ks * 8 + nt) * 64 + lane];
            acc[nt] = __builtin_amdgcn_mfma_f32_16x16x32_bf16(a, b, acc[nt], 0, 0, 0);
        }
    }
    // bias + leaky + LN -> hn (bf16) into private tile
    {
        float ba[8], gg[8], bb[8];
#pragma unroll
        for (int nt = 0; nt < 8; ++nt) {
            int col = nt * 16 + l15;
            ba[nt] = b2a[col]; gg[nt] = g2[col]; bb[nt] = be2[col];
        }
#pragma unroll
        for (int reg = 0; reg < 4; ++reg) {
            float v[8];
            float s = 0.f, q = 0.f;
#pragma unroll
            for (int nt = 0; nt < 8; ++nt) {
                float t = acc[nt][reg] + ba[nt];
                t = (t >= 0.f) ? t : NEG_SLOPE * t;
                v[nt] = t; s += t; q += t * t;
            }
#pragma unroll
            for (int off = 1; off < 16; off <<= 1) {
                s += __shfl_xor(s, off, 64);
                q += __shfl_xor(q, off, 64);
            }
            float mu  = s * (1.f / DO);
            float var = q * (1.f / DO) - mu * mu;
            float rs  = rsqrtf(var + LN_EPS);
            int lrow = quad * 4 + reg;
#pragma unroll
            for (int nt = 0; nt < 8; ++nt) {
                float h = (v[nt] - mu) * rs * gg[nt] + bb[nt];
                s_t[wave][lrow * T_LD + nt * 16 + l15] = f2bf(h);
            }
        }
    }

    // ===== GEMM2: out = hn @ W2b + b2b  (K=128, 4 slabs) =====
#pragma unroll
    for (int nt = 0; nt < 8; ++nt) acc[nt] = (f32x4){0.f, 0.f, 0.f, 0.f};
#pragma unroll
    for (int ks = 0; ks < 4; ++ks) {
        bf16x8 a = *(const bf16x8*)&s_t[wave][l15 * T_LD + ks * 32 + kq];
#pragma unroll
        for (int nt = 0; nt < 8; ++nt) {
            bf16x8 b = tW2b[(ks * 8 + nt) * 64 + lane];
            acc[nt] = __builtin_amdgcn_mfma_f32_16x16x32_bf16(a, b, acc[nt], 0, 0, 0);
        }
    }
    {
#pragma unroll
        for (int reg = 0; reg < 4; ++reg) {
            int nodeC = nbase + wave * 16 + quad * 4 + reg;
            if (nodeC < N) {
                long base = (long)nodeC * DO;
#pragma unroll
                for (int nt = 0; nt < 8; ++nt)
                    out[base + nt * 16 + l15] = acc[nt][reg] + b2b[nt * 16 + l15];
            }
        }
    }
}

// ---------------------------------------------------------------------------
extern "C" void kernel_launch(void* const* d_in, const int* in_sizes, int n_in,
                              void* d_out, int out_size, void* d_ws, size_t ws_size,
                              hipStream_t stream)
{
    const float* x          = (const float*)d_in[0];
    const int*   edge_index = (const int*)d_in[1];
    const float* edge_attr  = (const float*)d_in[2];
    const float* u          = (const float*)d_in[3];
    const float* W1a = (const float*)d_in[5];
    const float* b1a = (const float*)d_in[6];
    const float* g1  = (const float*)d_in[7];
    const float* be1 = (const float*)d_in[8];
    const float* W1b = (const float*)d_in[9];
    const float* b1b = (const float*)d_in[10];
    const float* W2a = (const float*)d_in[11];
    const float* b2a = (const float*)d_in[12];
    const float* g2  = (const float*)d_in[13];
    const float* be2 = (const float*)d_in[14];
    const float* W2b = (const float*)d_in[15];
    const float* b2b = (const float*)d_in[16];

    const int N = in_sizes[0] / DN;   // 50000
    const int E = in_sizes[2] / DE;   // 800000
    float* out  = (float*)d_out;

    // ws layout: sums [N*DO] f16 | cnt [N] f32 | frag table [23*512*8] bf16
    __half* sums = (__half*)d_ws;
    float*  cnt  = (float*)(sums + (size_t)N * DO);
    size_t tab_off = (size_t)N * DO * sizeof(__half) + (size_t)N * sizeof(float);
    tab_off = (tab_off + 15) & ~(size_t)15;
    unsigned short* tab = (unsigned short*)((char*)d_ws + tab_off);
    // footprint: 12.8MB + 0.2MB + 0.19MB = ~13.2MB, well under the 25.8MB
    // the R2 layout already proved available.

    (void)hipMemsetAsync(d_ws, 0,
                         (size_t)N * DO * sizeof(__half) + (size_t)N * sizeof(float),
                         stream);

    wprep_kernel<<<(23 * 512 + 255) / 256, 256, 0, stream>>>(W1a, W1b, W2a, W2b, tab);

    const int eblocks = (E + EPB - 1) / EPB;
    edge_kernel<<<eblocks, 256, 0, stream>>>(
        x, edge_index, edge_attr, u, tab, b1a, g1, be1, sums, cnt, E);

    const int nblocks = (N + NB - 1) / NB;
    node_kernel<<<nblocks, 256, 0, stream>>>(
        x, sums, cnt, tab, b1b, b2a, g2, be2, b2b, out, N);
}